// Round 16
// baseline (129.866 us; speedup 1.0000x reference)
//
#include <hip/hip_runtime.h>
#include <hip/hip_bf16.h>

#define BB 4
#define CIN 256
#define CO 64
#define HW_ 4096
#define SPLIT_A 8
#define SPLIT_S 8
#define DCHUNK_A (HW_ / SPLIT_A)   // 512
#define ECHUNK_S (HW_ / SPLIT_S)   // 512

typedef __attribute__((ext_vector_type(8))) short short8;
typedef __attribute__((ext_vector_type(4))) float f32x4;
typedef __attribute__((ext_vector_type(16))) float f32x16;
typedef __attribute__((ext_vector_type(4))) unsigned uint4v;
typedef __attribute__((ext_vector_type(2))) unsigned uint2v;

__device__ inline unsigned short f2bf(float f) {
  union { float f; unsigned u; } x; x.f = f;
  unsigned r = x.u + 0x7fffu + ((x.u >> 16) & 1u);  // RNE
  return (unsigned short)(r >> 16);
}
__device__ inline float bf2f(unsigned short h) {
  union { unsigned u; float f; } x; x.u = ((unsigned)h) << 16;
  return x.f;
}
__device__ inline unsigned packbf2(float a, float b) {
  __hip_bfloat162 t = __float22bfloat162_rn(float2{a, b});
  union { __hip_bfloat162 h; unsigned u; } c; c.h = t; return c.u;
}
__device__ inline void gl_lds16(const void* g, void* l) {
  __builtin_amdgcn_global_load_lds(
      (const __attribute__((address_space(1))) unsigned int*)g,
      (__attribute__((address_space(3))) unsigned int*)l, 16, 0, 0);
}

// ---------------------------------------------------------------------------
// K1: QKV projection as MFMA GEMM (r14-verified, unchanged).
// ---------------------------------------------------------------------------
__global__ __launch_bounds__(256, 3) void qkv_kernel(
    const float* __restrict__ x,
    const float* __restrict__ wq, const float* __restrict__ bq,
    const float* __restrict__ wk, const float* __restrict__ bk,
    const float* __restrict__ wv, const float* __restrict__ bv,
    unsigned short* __restrict__ qT, unsigned short* __restrict__ kT,
    unsigned short* __restrict__ v)
{
  const int b = blockIdx.z;
  const int which = blockIdx.y;
  const int n0 = blockIdx.x * 64;
  const int tid = threadIdx.x;
  const int w = tid >> 6, lane = tid & 63;
  const int lq = lane & 15, quad = lane >> 4;

  const float* W  = (which == 0) ? wq : (which == 1) ? wk : wv;
  const float* Bb = (which == 0) ? bq : (which == 1) ? bk : bv;

  __shared__ unsigned short w_lds[64 * 256];
  unsigned char* wbytes = reinterpret_cast<unsigned char*>(w_lds);

#pragma unroll
  for (int i = 0; i < 16; ++i) {
    int L = i * 256 + tid;
    int row = L >> 6, col4 = L & 63;
    float4 w4 = *reinterpret_cast<const float4*>(&W[row * 256 + col4 * 4]);
    ushort4 p;
    p.x = f2bf(w4.x); p.y = f2bf(w4.y); p.z = f2bf(w4.z); p.w = f2bf(w4.w);
    int addr = (row * 512 + col4 * 8) ^ ((row & 7) << 4);
    *reinterpret_cast<ushort4*>(wbytes + addr) = p;
  }
  __syncthreads();

  const int n = n0 + w * 16 + lq;
  const float* xb = x + (size_t)b * CIN * HW_ + n;

  const f32x4 zero = {0.f, 0.f, 0.f, 0.f};
  f32x4 acc[4];
#pragma unroll
  for (int mt = 0; mt < 4; ++mt) acc[mt] = zero;

  for (int ks = 0; ks < 8; ++ks) {
    float xv[8];
#pragma unroll
    for (int j = 0; j < 8; ++j)
      xv[j] = xb[(size_t)(ks * 32 + quad * 8 + j) * HW_];
    short8 bhi, blo;
#pragma unroll
    for (int j = 0; j < 8; ++j) {
      unsigned short h = f2bf(xv[j]);
      bhi[j] = (short)h;
      blo[j] = (short)f2bf(xv[j] - bf2f(h));
    }
#pragma unroll
    for (int mt = 0; mt < 4; ++mt) {
      int addr = ((mt * 16 + lq) * 512 + ks * 64 + quad * 16) ^ ((lq & 7) << 4);
      short8 af = *reinterpret_cast<const short8*>(wbytes + addr);
      acc[mt] = __builtin_amdgcn_mfma_f32_16x16x32_bf16(af, bhi, acc[mt], 0, 0, 0);
      acc[mt] = __builtin_amdgcn_mfma_f32_16x16x32_bf16(af, blo, acc[mt], 0, 0, 0);
    }
  }

  float4 bias4[4];
#pragma unroll
  for (int mt = 0; mt < 4; ++mt)
    bias4[mt] = *reinterpret_cast<const float4*>(&Bb[mt * 16 + quad * 4]);

  if (which < 2) {
    unsigned short* outp = ((which == 0) ? qT : kT) + ((size_t)b * HW_ + n) * 64;
#pragma unroll
    for (int mt = 0; mt < 4; ++mt) {
      ushort4 p;
      p.x = f2bf(acc[mt][0] + bias4[mt].x);
      p.y = f2bf(acc[mt][1] + bias4[mt].y);
      p.z = f2bf(acc[mt][2] + bias4[mt].z);
      p.w = f2bf(acc[mt][3] + bias4[mt].w);
      *reinterpret_cast<ushort4*>(&outp[mt * 16 + quad * 4]) = p;
    }
  } else {
#pragma unroll
    for (int mt = 0; mt < 4; ++mt) {
      float bb[4] = {bias4[mt].x, bias4[mt].y, bias4[mt].z, bias4[mt].w};
#pragma unroll
      for (int r = 0; r < 4; ++r)
        v[((size_t)b * CO + mt * 16 + quad * 4 + r) * HW_ + n] = f2bf(acc[mt][r] + bb[r]);
    }
  }
}

// ---------------------------------------------------------------------------
// K2a: stats (r14-verified, unchanged). K tile staged via global_load_lds.
// ---------------------------------------------------------------------------
__global__ __launch_bounds__(256, 3) void stats_kernel(
    const unsigned short* __restrict__ qT,
    const unsigned short* __restrict__ kT,
    float2* __restrict__ parts)
{
  const int id = blockIdx.x;
  const int sw = (id & 7) * 128 + (id >> 3);   // XCD swizzle (1024 blocks)
  const int dtile = sw & 31;
  const int esplit = (sw >> 5) & 7;
  const int b = sw >> 8;
  const int tid = threadIdx.x;
  const int w = tid >> 6, lane = tid & 63;
  const int lo = lane & 31, h = lane >> 5;

  __shared__ __align__(16) unsigned char k_lds[128 * 128];  // [128 e][64 c] swz

  const size_t base = (size_t)b * HW_ * CO;
  const int d0 = dtile * 128 + w * 32;

  short8 qf[4];
#pragma unroll
  for (int ks = 0; ks < 4; ++ks)
    qf[ks] = *reinterpret_cast<const short8*>(&qT[base + (size_t)(d0 + lo) * 64 + ks * 16 + h * 8]);

  float m_run = -3.0e38f, l_run = 0.f;
  const char* kT_bytes = reinterpret_cast<const char*>(kT) + base * 2;
  const int e_beg = esplit * ECHUNK_S;

  for (int eb = e_beg; eb < e_beg + ECHUNK_S; eb += 128) {
#pragma unroll
    for (int j = 0; j < 4; ++j) {
      int chunk = w * 4 + j;
      int row = chunk * 8 + (lane >> 3);
      int cp = (lane & 7) * 16;
      gl_lds16(kT_bytes + (size_t)(eb + row) * 128 + (cp ^ ((row & 7) << 4)),
               k_lds + chunk * 1024);
    }
    __syncthreads();

#pragma unroll
    for (int et = 0; et < 4; ++et) {
      const int er = et * 32 + lo;
      f32x16 T;
#pragma unroll
      for (int i = 0; i < 16; ++i) T[i] = 0.f;
#pragma unroll
      for (int ks = 0; ks < 4; ++ks) {
        const short8 kfr = *reinterpret_cast<const short8*>(
            k_lds + er * 128 + ((ks * 32 + h * 16) ^ ((er & 7) << 4)));
        T = __builtin_amdgcn_mfma_f32_32x32x16_bf16(kfr, qf[ks], T, 0, 0, 0);
      }
      float tmax = T[0];
#pragma unroll
      for (int r = 1; r < 16; ++r) tmax = fmaxf(tmax, T[r]);
      tmax = fmaxf(tmax, __shfl_xor(tmax, 32));
      float m_new = fmaxf(m_run, tmax);
      float lsum = 0.f;
#pragma unroll
      for (int r = 0; r < 16; ++r) lsum += __expf(T[r] - m_new);
      lsum += __shfl_xor(lsum, 32);
      l_run = l_run * __expf(m_run - m_new) + lsum;
      m_run = m_new;
    }
    __syncthreads();
  }
  if (h == 0)
    parts[((size_t)b * HW_ + d0 + lo) * SPLIT_S + esplit] = make_float2(m_run, l_run);
}

// ---------------------------------------------------------------------------
// K2b: merge per-split stats (exact).
// ---------------------------------------------------------------------------
__global__ __launch_bounds__(256) void combine_kernel(
    const float2* __restrict__ parts, float* __restrict__ ml)
{
  const int r = blockIdx.x * 256 + threadIdx.x;
  float2 p[SPLIT_S];
#pragma unroll
  for (int i = 0; i < SPLIT_S; ++i) p[i] = parts[(size_t)r * SPLIT_S + i];
  float M = p[0].x;
#pragma unroll
  for (int i = 1; i < SPLIT_S; ++i) M = fmaxf(M, p[i].x);
  float L = 0.f;
#pragma unroll
  for (int i = 0; i < SPLIT_S; ++i) L += p[i].y * __expf(p[i].x - M);
  ml[r] = M + __logf(L);
}

// ---------------------------------------------------------------------------
// K3: apply (r14-verified, unchanged). global_load_lds staging, 32x32 MFMA,
// in-register P via packbf2+permlane32_swap, full-line NT epilogue.
// ---------------------------------------------------------------------------
__global__ __launch_bounds__(256, 3) void apply_kernel(
    const unsigned short* __restrict__ qT,
    const unsigned short* __restrict__ kT,
    const unsigned short* __restrict__ vv,
    const float* __restrict__ ml,
    unsigned short* __restrict__ Opart)
{
  const int id = blockIdx.x;
  const int sw = (id & 7) * 128 + (id >> 3);   // XCD swizzle (1024 blocks)
  const int et = sw & 31;
  const int split = (sw >> 5) & 7;
  const int b = sw >> 8;
  const int tid = threadIdx.x;
  const int w = tid >> 6, lane = tid & 63;
  const int lo = lane & 31, h = lane >> 5;

  __shared__ __align__(16) unsigned char q_lds[128 * 128];   // [128 d][64 c] swz
  __shared__ __align__(16) unsigned char v_lds[64 * 256];    // [64 c][128 d] swz

  const size_t base = (size_t)b * HW_ * CO;
  const int e0 = et * 128;
  const int e = e0 + w * 32 + lo;

  short8 kf[4];
#pragma unroll
  for (int ks = 0; ks < 4; ++ks)
    kf[ks] = *reinterpret_cast<const short8*>(&kT[base + (size_t)e * 64 + ks * 16 + h * 8]);

  f32x16 Of0, Of1;
#pragma unroll
  for (int i = 0; i < 16; ++i) { Of0[i] = 0.f; Of1[i] = 0.f; }

  const char* qT_bytes = reinterpret_cast<const char*>(qT) + base * 2;
  const char* v_bytes = reinterpret_cast<const char*>(vv) + base * 2;
  const float* mlb = ml + (size_t)b * HW_;

  const int d_beg = split * DCHUNK_A;
  for (int dt = d_beg; dt < d_beg + DCHUNK_A; dt += 128) {
#pragma unroll
    for (int j = 0; j < 4; ++j) {
      int chunk = w * 4 + j;
      {
        int row = chunk * 8 + (lane >> 3);
        int cp = (lane & 7) * 16;
        gl_lds16(qT_bytes + (size_t)(dt + row) * 128 + (cp ^ ((row & 7) << 4)),
                 q_lds + chunk * 1024);
      }
      {
        int vrow = chunk * 4 + (lane >> 4);
        int cp = (lane & 15) * 16;
        gl_lds16(v_bytes + (size_t)vrow * 8192 + dt * 2 + (cp ^ ((vrow & 15) << 4)),
                 v_lds + chunk * 1024);
      }
    }
    __syncthreads();

#pragma unroll
    for (int nt = 0; nt < 4; ++nt) {
      const int db = dt + nt * 32;
      const int lrow = nt * 32 + lo;
      f32x16 T;
#pragma unroll
      for (int i = 0; i < 16; ++i) T[i] = 0.f;
#pragma unroll
      for (int ks = 0; ks < 4; ++ks) {
        const short8 qfr = *reinterpret_cast<const short8*>(
            q_lds + lrow * 128 + ((ks * 32 + h * 16) ^ ((lrow & 7) << 4)));
        T = __builtin_amdgcn_mfma_f32_32x32x16_bf16(qfr, kf[ks], T, 0, 0, 0);
      }
      float p[16];
#pragma unroll
      for (int q = 0; q < 4; ++q) {
        f32x4 m4 = *reinterpret_cast<const f32x4*>(&mlb[db + q * 8 + h * 4]);
#pragma unroll
        for (int r = 0; r < 4; ++r)
          p[q * 4 + r] = __expf(T[q * 4 + r] - m4[r]);
      }
      unsigned pk[8];
#pragma unroll
      for (int m = 0; m < 8; ++m) pk[m] = packbf2(p[2 * m], p[2 * m + 1]);
#pragma unroll
      for (int kk = 0; kk < 2; ++kk) {
        uint2v s0 = __builtin_amdgcn_permlane32_swap(pk[kk * 4 + 0], pk[kk * 4 + 2], false, false);
        uint2v s1 = __builtin_amdgcn_permlane32_swap(pk[kk * 4 + 1], pk[kk * 4 + 3], false, false);
        uint4v pw_;
        pw_[0] = s0[0]; pw_[1] = s1[0]; pw_[2] = s0[1]; pw_[3] = s1[1];
        const short8 pf = *reinterpret_cast<const short8*>(&pw_);
        const int dcol = (nt * 32 + kk * 16) * 2 + h * 16;
        {
          const int row = lo;
          const short8 vf = *reinterpret_cast<const short8*>(
              v_lds + row * 256 + (dcol ^ ((row & 15) << 4)));
          Of0 = __builtin_amdgcn_mfma_f32_32x32x16_bf16(vf, pf, Of0, 0, 0, 0);
        }
        {
          const int row = 32 + lo;
          const short8 vf = *reinterpret_cast<const short8*>(
              v_lds + row * 256 + (dcol ^ ((row & 15) << 4)));
          Of1 = __builtin_amdgcn_mfma_f32_32x32x16_bf16(vf, pf, Of1, 0, 0, 0);
        }
      }
    }
    __syncthreads();
  }

  // epilogue: transpose via LDS (overlay q_lds), full-line NT stores
  unsigned short* o_lds = reinterpret_cast<unsigned short*>(q_lds);  // [64 c][128 e]
#pragma unroll
  for (int reg = 0; reg < 16; ++reg) {
    int rr = (reg & 3) + 8 * (reg >> 2) + 4 * h;
    o_lds[rr * 128 + w * 32 + lo] = f2bf(Of0[reg]);
    o_lds[(32 + rr) * 128 + w * 32 + lo] = f2bf(Of1[reg]);
  }
  __syncthreads();
  {
    const int c = tid >> 4;            // 0..15
    const int ee = (tid & 15) * 8;     // 16B/lane; 16 lanes = 256B contiguous
#pragma unroll
    for (int p = 0; p < 4; ++p) {
      int cc = p * 16 + c;
      f32x4 wv_ = *reinterpret_cast<const f32x4*>(&o_lds[cc * 128 + ee]);
      __builtin_nontemporal_store(wv_, reinterpret_cast<f32x4*>(
          &Opart[((size_t)(b * SPLIT_A + split) * CO + cc) * HW_ + e0 + ee]));
    }
  }
}

// ---------------------------------------------------------------------------
// K4: outproj, LDS-staged. One block per (64-d, b); split-summed O staged in
// LDS once (FETCH 134 -> 17 MB, amplification 8 -> 1), then all 256 f rows
// computed from LDS. wo stays on the wave-uniform scalar-load path.
// ---------------------------------------------------------------------------
__global__ __launch_bounds__(256) void outproj_kernel(
    const unsigned short* __restrict__ Opart, const float* __restrict__ wo,
    const float* __restrict__ bo, float* __restrict__ out)
{
  const int b = blockIdx.y;
  const int d0 = blockIdx.x * 64;
  const int tid = threadIdx.x;

  __shared__ __align__(16) float olds[64 * 68];   // [64 c][64 d + pad4]

  // stage: sum the 8 splits into registers, then one LDS write per position
  {
    const int cr = tid >> 3;          // 0..31
    const int dc = (tid & 7) * 8;     // 0..56
    float a0[8], a1[8];
#pragma unroll
    for (int k = 0; k < 8; ++k) { a0[k] = 0.f; a1[k] = 0.f; }
    const unsigned short* Ob = Opart + (size_t)b * SPLIT_A * CO * HW_;
#pragma unroll
    for (int s = 0; s < SPLIT_A; ++s) {
      const unsigned short* p0 = &Ob[((size_t)s * CO + cr) * HW_ + d0 + dc];
      const unsigned short* p1 = &Ob[((size_t)s * CO + cr + 32) * HW_ + d0 + dc];
      uint4v u0 = *reinterpret_cast<const uint4v*>(p0);
      uint4v u1 = *reinterpret_cast<const uint4v*>(p1);
#pragma unroll
      for (int k = 0; k < 4; ++k) {
        a0[2 * k]     += bf2f((unsigned short)(u0[k] & 0xffffu));
        a0[2 * k + 1] += bf2f((unsigned short)(u0[k] >> 16));
        a1[2 * k]     += bf2f((unsigned short)(u1[k] & 0xffffu));
        a1[2 * k + 1] += bf2f((unsigned short)(u1[k] >> 16));
      }
    }
#pragma unroll
    for (int k = 0; k < 8; ++k) {
      olds[cr * 68 + dc + k] = a0[k];
      olds[(cr + 32) * 68 + dc + k] = a1[k];
    }
  }
  __syncthreads();

  // compute: wave fg owns f rows [fg*64, fg*64+64); lane = d
  const int fg = tid >> 6, d = tid & 63;
  float acc[64];
#pragma unroll
  for (int j = 0; j < 64; ++j) acc[j] = bo[fg * 64 + j];
#pragma unroll 4
  for (int c = 0; c < CO; ++c) {
    float ov = olds[c * 68 + d];
#pragma unroll
    for (int j = 0; j < 64; ++j)
      acc[j] = fmaf(wo[(size_t)(fg * 64 + j) * CO + c], ov, acc[j]);
  }
#pragma unroll
  for (int j = 0; j < 64; ++j)
    out[((size_t)b * CIN + fg * 64 + j) * HW_ + d0 + d] = acc[j];
}

extern "C" void kernel_launch(void* const* d_in, const int* in_sizes, int n_in,
                              void* d_out, int out_size, void* d_ws, size_t ws_size,
                              hipStream_t stream) {
  const float* x  = (const float*)d_in[0];
  const float* wq = (const float*)d_in[1];
  const float* bq = (const float*)d_in[2];
  const float* wk = (const float*)d_in[3];
  const float* bk = (const float*)d_in[4];
  const float* wv = (const float*)d_in[5];
  const float* bv = (const float*)d_in[6];
  const float* wo = (const float*)d_in[7];
  const float* bo = (const float*)d_in[8];
  float* out = (float*)d_out;

  char* ws = (char*)d_ws;
  unsigned short* qT    = (unsigned short*)(ws);               // 2 MB   [b][4096][64] bf16
  unsigned short* kT    = (unsigned short*)(ws + (2u << 20));  // 2 MB   [b][4096][64] bf16
  unsigned short* v     = (unsigned short*)(ws + (4u << 20));  // 2 MB   [b][64][4096] bf16
  unsigned short* Opart = (unsigned short*)(ws + (6u << 20));  // 16.8MB [b][8][64][4096] bf16
  float* ml             = (float*)(ws + (23u << 20));          // 64 KB  [b][4096] f32
  float2* parts         = (float2*)(ws + (24u << 20));         // 1 MB   [b][4096][8] float2

  qkv_kernel<<<dim3(64, 3, 4), 256, 0, stream>>>(x, wq, bq, wk, bk, wv, bv, qT, kT, v);
  stats_kernel<<<dim3(1024), 256, 0, stream>>>(qT, kT, parts);
  combine_kernel<<<dim3(BB * HW_ / 256), 256, 0, stream>>>(parts, ml);
  apply_kernel<<<dim3(1024), 256, 0, stream>>>(qT, kT, v, ml, Opart);
  outproj_kernel<<<dim3(64, 4), 256, 0, stream>>>(Opart, wo, bo, out);
}

// Round 17
// 79.721 us; speedup vs baseline: 1.6290x; 1.6290x over previous
//
#include <hip/hip_runtime.h>
#include <hip/hip_bf16.h>

#define BB 4
#define CIN 256
#define CO 64
#define HW_ 4096
#define SPLIT_A 8
#define SPLIT_S 8
#define DCHUNK_A (HW_ / SPLIT_A)   // 512
#define ECHUNK_S (HW_ / SPLIT_S)   // 512

typedef __attribute__((ext_vector_type(8))) short short8;
typedef __attribute__((ext_vector_type(4))) float f32x4;
typedef __attribute__((ext_vector_type(16))) float f32x16;
typedef __attribute__((ext_vector_type(4))) unsigned uint4v;
typedef __attribute__((ext_vector_type(2))) unsigned uint2v;

__device__ inline unsigned short f2bf(float f) {
  union { float f; unsigned u; } x; x.f = f;
  unsigned r = x.u + 0x7fffu + ((x.u >> 16) & 1u);  // RNE
  return (unsigned short)(r >> 16);
}
__device__ inline float bf2f(unsigned short h) {
  union { unsigned u; float f; } x; x.u = ((unsigned)h) << 16;
  return x.f;
}
__device__ inline unsigned packbf2(float a, float b) {
  __hip_bfloat162 t = __float22bfloat162_rn(float2{a, b});
  union { __hip_bfloat162 h; unsigned u; } c; c.h = t; return c.u;
}
__device__ inline void gl_lds16(const void* g, void* l) {
  __builtin_amdgcn_global_load_lds(
      (const __attribute__((address_space(1))) unsigned int*)g,
      (__attribute__((address_space(3))) unsigned int*)l, 16, 0, 0);
}

// ---------------------------------------------------------------------------
// K1: QKV projection as MFMA GEMM (r14-verified, unchanged).
// ---------------------------------------------------------------------------
__global__ __launch_bounds__(256, 3) void qkv_kernel(
    const float* __restrict__ x,
    const float* __restrict__ wq, const float* __restrict__ bq,
    const float* __restrict__ wk, const float* __restrict__ bk,
    const float* __restrict__ wv, const float* __restrict__ bv,
    unsigned short* __restrict__ qT, unsigned short* __restrict__ kT,
    unsigned short* __restrict__ v)
{
  const int b = blockIdx.z;
  const int which = blockIdx.y;
  const int n0 = blockIdx.x * 64;
  const int tid = threadIdx.x;
  const int w = tid >> 6, lane = tid & 63;
  const int lq = lane & 15, quad = lane >> 4;

  const float* W  = (which == 0) ? wq : (which == 1) ? wk : wv;
  const float* Bb = (which == 0) ? bq : (which == 1) ? bk : bv;

  __shared__ unsigned short w_lds[64 * 256];
  unsigned char* wbytes = reinterpret_cast<unsigned char*>(w_lds);

#pragma unroll
  for (int i = 0; i < 16; ++i) {
    int L = i * 256 + tid;
    int row = L >> 6, col4 = L & 63;
    float4 w4 = *reinterpret_cast<const float4*>(&W[row * 256 + col4 * 4]);
    ushort4 p;
    p.x = f2bf(w4.x); p.y = f2bf(w4.y); p.z = f2bf(w4.z); p.w = f2bf(w4.w);
    int addr = (row * 512 + col4 * 8) ^ ((row & 7) << 4);
    *reinterpret_cast<ushort4*>(wbytes + addr) = p;
  }
  __syncthreads();

  const int n = n0 + w * 16 + lq;
  const float* xb = x + (size_t)b * CIN * HW_ + n;

  const f32x4 zero = {0.f, 0.f, 0.f, 0.f};
  f32x4 acc[4];
#pragma unroll
  for (int mt = 0; mt < 4; ++mt) acc[mt] = zero;

  for (int ks = 0; ks < 8; ++ks) {
    float xv[8];
#pragma unroll
    for (int j = 0; j < 8; ++j)
      xv[j] = xb[(size_t)(ks * 32 + quad * 8 + j) * HW_];
    short8 bhi, blo;
#pragma unroll
    for (int j = 0; j < 8; ++j) {
      unsigned short h = f2bf(xv[j]);
      bhi[j] = (short)h;
      blo[j] = (short)f2bf(xv[j] - bf2f(h));
    }
#pragma unroll
    for (int mt = 0; mt < 4; ++mt) {
      int addr = ((mt * 16 + lq) * 512 + ks * 64 + quad * 16) ^ ((lq & 7) << 4);
      short8 af = *reinterpret_cast<const short8*>(wbytes + addr);
      acc[mt] = __builtin_amdgcn_mfma_f32_16x16x32_bf16(af, bhi, acc[mt], 0, 0, 0);
      acc[mt] = __builtin_amdgcn_mfma_f32_16x16x32_bf16(af, blo, acc[mt], 0, 0, 0);
    }
  }

  float4 bias4[4];
#pragma unroll
  for (int mt = 0; mt < 4; ++mt)
    bias4[mt] = *reinterpret_cast<const float4*>(&Bb[mt * 16 + quad * 4]);

  if (which < 2) {
    unsigned short* outp = ((which == 0) ? qT : kT) + ((size_t)b * HW_ + n) * 64;
#pragma unroll
    for (int mt = 0; mt < 4; ++mt) {
      ushort4 p;
      p.x = f2bf(acc[mt][0] + bias4[mt].x);
      p.y = f2bf(acc[mt][1] + bias4[mt].y);
      p.z = f2bf(acc[mt][2] + bias4[mt].z);
      p.w = f2bf(acc[mt][3] + bias4[mt].w);
      *reinterpret_cast<ushort4*>(&outp[mt * 16 + quad * 4]) = p;
    }
  } else {
#pragma unroll
    for (int mt = 0; mt < 4; ++mt) {
      float bb[4] = {bias4[mt].x, bias4[mt].y, bias4[mt].z, bias4[mt].w};
#pragma unroll
      for (int r = 0; r < 4; ++r)
        v[((size_t)b * CO + mt * 16 + quad * 4 + r) * HW_ + n] = f2bf(acc[mt][r] + bb[r]);
    }
  }
}

// ---------------------------------------------------------------------------
// K2a: stats (r14-verified, unchanged). K tile staged via global_load_lds.
// ---------------------------------------------------------------------------
__global__ __launch_bounds__(256, 3) void stats_kernel(
    const unsigned short* __restrict__ qT,
    const unsigned short* __restrict__ kT,
    float2* __restrict__ parts)
{
  const int id = blockIdx.x;
  const int sw = (id & 7) * 128 + (id >> 3);   // XCD swizzle (1024 blocks)
  const int dtile = sw & 31;
  const int esplit = (sw >> 5) & 7;
  const int b = sw >> 8;
  const int tid = threadIdx.x;
  const int w = tid >> 6, lane = tid & 63;
  const int lo = lane & 31, h = lane >> 5;

  __shared__ __align__(16) unsigned char k_lds[128 * 128];  // [128 e][64 c] swz

  const size_t base = (size_t)b * HW_ * CO;
  const int d0 = dtile * 128 + w * 32;

  short8 qf[4];
#pragma unroll
  for (int ks = 0; ks < 4; ++ks)
    qf[ks] = *reinterpret_cast<const short8*>(&qT[base + (size_t)(d0 + lo) * 64 + ks * 16 + h * 8]);

  float m_run = -3.0e38f, l_run = 0.f;
  const char* kT_bytes = reinterpret_cast<const char*>(kT) + base * 2;
  const int e_beg = esplit * ECHUNK_S;

  for (int eb = e_beg; eb < e_beg + ECHUNK_S; eb += 128) {
#pragma unroll
    for (int j = 0; j < 4; ++j) {
      int chunk = w * 4 + j;
      int row = chunk * 8 + (lane >> 3);
      int cp = (lane & 7) * 16;
      gl_lds16(kT_bytes + (size_t)(eb + row) * 128 + (cp ^ ((row & 7) << 4)),
               k_lds + chunk * 1024);
    }
    __syncthreads();

#pragma unroll
    for (int et = 0; et < 4; ++et) {
      const int er = et * 32 + lo;
      f32x16 T;
#pragma unroll
      for (int i = 0; i < 16; ++i) T[i] = 0.f;
#pragma unroll
      for (int ks = 0; ks < 4; ++ks) {
        const short8 kfr = *reinterpret_cast<const short8*>(
            k_lds + er * 128 + ((ks * 32 + h * 16) ^ ((er & 7) << 4)));
        T = __builtin_amdgcn_mfma_f32_32x32x16_bf16(kfr, qf[ks], T, 0, 0, 0);
      }
      float tmax = T[0];
#pragma unroll
      for (int r = 1; r < 16; ++r) tmax = fmaxf(tmax, T[r]);
      tmax = fmaxf(tmax, __shfl_xor(tmax, 32));
      float m_new = fmaxf(m_run, tmax);
      float lsum = 0.f;
#pragma unroll
      for (int r = 0; r < 16; ++r) lsum += __expf(T[r] - m_new);
      lsum += __shfl_xor(lsum, 32);
      l_run = l_run * __expf(m_run - m_new) + lsum;
      m_run = m_new;
    }
    __syncthreads();
  }
  if (h == 0)
    parts[((size_t)b * HW_ + d0 + lo) * SPLIT_S + esplit] = make_float2(m_run, l_run);
}

// ---------------------------------------------------------------------------
// K2b: merge per-split stats (exact).
// ---------------------------------------------------------------------------
__global__ __launch_bounds__(256) void combine_kernel(
    const float2* __restrict__ parts, float* __restrict__ ml)
{
  const int r = blockIdx.x * 256 + threadIdx.x;
  float2 p[SPLIT_S];
#pragma unroll
  for (int i = 0; i < SPLIT_S; ++i) p[i] = parts[(size_t)r * SPLIT_S + i];
  float M = p[0].x;
#pragma unroll
  for (int i = 1; i < SPLIT_S; ++i) M = fmaxf(M, p[i].x);
  float L = 0.f;
#pragma unroll
  for (int i = 0; i < SPLIT_S; ++i) L += p[i].y * __expf(p[i].x - M);
  ml[r] = M + __logf(L);
}

// ---------------------------------------------------------------------------
// K3: apply (r14-verified, unchanged). global_load_lds staging, 32x32 MFMA,
// in-register P via packbf2+permlane32_swap, full-line NT epilogue.
// ---------------------------------------------------------------------------
__global__ __launch_bounds__(256, 3) void apply_kernel(
    const unsigned short* __restrict__ qT,
    const unsigned short* __restrict__ kT,
    const unsigned short* __restrict__ vv,
    const float* __restrict__ ml,
    unsigned short* __restrict__ Opart)
{
  const int id = blockIdx.x;
  const int sw = (id & 7) * 128 + (id >> 3);   // XCD swizzle (1024 blocks)
  const int et = sw & 31;
  const int split = (sw >> 5) & 7;
  const int b = sw >> 8;
  const int tid = threadIdx.x;
  const int w = tid >> 6, lane = tid & 63;
  const int lo = lane & 31, h = lane >> 5;

  __shared__ __align__(16) unsigned char q_lds[128 * 128];   // [128 d][64 c] swz
  __shared__ __align__(16) unsigned char v_lds[64 * 256];    // [64 c][128 d] swz

  const size_t base = (size_t)b * HW_ * CO;
  const int e0 = et * 128;
  const int e = e0 + w * 32 + lo;

  short8 kf[4];
#pragma unroll
  for (int ks = 0; ks < 4; ++ks)
    kf[ks] = *reinterpret_cast<const short8*>(&kT[base + (size_t)e * 64 + ks * 16 + h * 8]);

  f32x16 Of0, Of1;
#pragma unroll
  for (int i = 0; i < 16; ++i) { Of0[i] = 0.f; Of1[i] = 0.f; }

  const char* qT_bytes = reinterpret_cast<const char*>(qT) + base * 2;
  const char* v_bytes = reinterpret_cast<const char*>(vv) + base * 2;
  const float* mlb = ml + (size_t)b * HW_;

  const int d_beg = split * DCHUNK_A;
  for (int dt = d_beg; dt < d_beg + DCHUNK_A; dt += 128) {
#pragma unroll
    for (int j = 0; j < 4; ++j) {
      int chunk = w * 4 + j;
      {
        int row = chunk * 8 + (lane >> 3);
        int cp = (lane & 7) * 16;
        gl_lds16(qT_bytes + (size_t)(dt + row) * 128 + (cp ^ ((row & 7) << 4)),
                 q_lds + chunk * 1024);
      }
      {
        int vrow = chunk * 4 + (lane >> 4);
        int cp = (lane & 15) * 16;
        gl_lds16(v_bytes + (size_t)vrow * 8192 + dt * 2 + (cp ^ ((vrow & 15) << 4)),
                 v_lds + chunk * 1024);
      }
    }
    __syncthreads();

#pragma unroll
    for (int nt = 0; nt < 4; ++nt) {
      const int db = dt + nt * 32;
      const int lrow = nt * 32 + lo;
      f32x16 T;
#pragma unroll
      for (int i = 0; i < 16; ++i) T[i] = 0.f;
#pragma unroll
      for (int ks = 0; ks < 4; ++ks) {
        const short8 qfr = *reinterpret_cast<const short8*>(
            q_lds + lrow * 128 + ((ks * 32 + h * 16) ^ ((lrow & 7) << 4)));
        T = __builtin_amdgcn_mfma_f32_32x32x16_bf16(qfr, kf[ks], T, 0, 0, 0);
      }
      float p[16];
#pragma unroll
      for (int q = 0; q < 4; ++q) {
        f32x4 m4 = *reinterpret_cast<const f32x4*>(&mlb[db + q * 8 + h * 4]);
#pragma unroll
        for (int r = 0; r < 4; ++r)
          p[q * 4 + r] = __expf(T[q * 4 + r] - m4[r]);
      }
      unsigned pk[8];
#pragma unroll
      for (int m = 0; m < 8; ++m) pk[m] = packbf2(p[2 * m], p[2 * m + 1]);
#pragma unroll
      for (int kk = 0; kk < 2; ++kk) {
        uint2v s0 = __builtin_amdgcn_permlane32_swap(pk[kk * 4 + 0], pk[kk * 4 + 2], false, false);
        uint2v s1 = __builtin_amdgcn_permlane32_swap(pk[kk * 4 + 1], pk[kk * 4 + 3], false, false);
        uint4v pw_;
        pw_[0] = s0[0]; pw_[1] = s1[0]; pw_[2] = s0[1]; pw_[3] = s1[1];
        const short8 pf = *reinterpret_cast<const short8*>(&pw_);
        const int dcol = (nt * 32 + kk * 16) * 2 + h * 16;
        {
          const int row = lo;
          const short8 vf = *reinterpret_cast<const short8*>(
              v_lds + row * 256 + (dcol ^ ((row & 15) << 4)));
          Of0 = __builtin_amdgcn_mfma_f32_32x32x16_bf16(vf, pf, Of0, 0, 0, 0);
        }
        {
          const int row = 32 + lo;
          const short8 vf = *reinterpret_cast<const short8*>(
              v_lds + row * 256 + (dcol ^ ((row & 15) << 4)));
          Of1 = __builtin_amdgcn_mfma_f32_32x32x16_bf16(vf, pf, Of1, 0, 0, 0);
        }
      }
    }
    __syncthreads();
  }

  // epilogue: transpose via LDS (overlay q_lds), full-line NT stores
  unsigned short* o_lds = reinterpret_cast<unsigned short*>(q_lds);  // [64 c][128 e]
#pragma unroll
  for (int reg = 0; reg < 16; ++reg) {
    int rr = (reg & 3) + 8 * (reg >> 2) + 4 * h;
    o_lds[rr * 128 + w * 32 + lo] = f2bf(Of0[reg]);
    o_lds[(32 + rr) * 128 + w * 32 + lo] = f2bf(Of1[reg]);
  }
  __syncthreads();
  {
    const int c = tid >> 4;            // 0..15
    const int ee = (tid & 15) * 8;     // 16B/lane; 16 lanes = 256B contiguous
#pragma unroll
    for (int p = 0; p < 4; ++p) {
      int cc = p * 16 + c;
      f32x4 wv_ = *reinterpret_cast<const f32x4*>(&o_lds[cc * 128 + ee]);
      __builtin_nontemporal_store(wv_, reinterpret_cast<f32x4*>(
          &Opart[((size_t)(b * SPLIT_A + split) * CO + cc) * HW_ + e0 + ee]));
    }
  }
}

// ---------------------------------------------------------------------------
// K4: outproj as MFMA GEMM (qkv pattern). out[f,d] = sum_{s,c} wo[f,c] *
// Opart[s,c,d] + bo[f]. Block = 128 f x 64 d; wo panel in LDS as bf16 hi+lo
// (f32-accurate); A-frags preloaded per ks (DS:MFMA = 1:4); B-frags per-lane
// coalesced ushort loads, s-loop unrolled for pipelining.
// ---------------------------------------------------------------------------
__global__ __launch_bounds__(256) void outproj_kernel(
    const unsigned short* __restrict__ Opart, const float* __restrict__ wo,
    const float* __restrict__ bo, float* __restrict__ out)
{
  const int b = blockIdx.z;
  const int fh = blockIdx.y;           // f rows [fh*128, fh*128+128)
  const int n0 = blockIdx.x * 64;      // d base
  const int tid = threadIdx.x;
  const int w = tid >> 6, lane = tid & 63;
  const int lq = lane & 15, quad = lane >> 4;

  __shared__ __align__(16) unsigned short whi_lds[128 * 64];  // 16 KB swz
  __shared__ __align__(16) unsigned short wlo_lds[128 * 64];  // 16 KB swz
  unsigned char* whb = reinterpret_cast<unsigned char*>(whi_lds);
  unsigned char* wlb = reinterpret_cast<unsigned char*>(wlo_lds);

  // stage wo panel [128 f][64 c] as bf16 hi/lo, swizzled
#pragma unroll
  for (int i = 0; i < 8; ++i) {
    int L = i * 256 + tid;             // float4 idx: row = L>>4, col4 = L&15
    int row = L >> 4, col4 = L & 15;
    float4 w4 = *reinterpret_cast<const float4*>(&wo[(size_t)(fh * 128 + row) * 64 + col4 * 4]);
    ushort4 hi, lo;
    hi.x = f2bf(w4.x); lo.x = f2bf(w4.x - bf2f(hi.x));
    hi.y = f2bf(w4.y); lo.y = f2bf(w4.y - bf2f(hi.y));
    hi.z = f2bf(w4.z); lo.z = f2bf(w4.z - bf2f(hi.z));
    hi.w = f2bf(w4.w); lo.w = f2bf(w4.w - bf2f(hi.w));
    int addr = (row * 128 + col4 * 8) ^ ((row & 7) << 4);
    *reinterpret_cast<ushort4*>(whb + addr) = hi;
    *reinterpret_cast<ushort4*>(wlb + addr) = lo;
  }
  __syncthreads();

  const int n = n0 + w * 16 + lq;      // this lane's d column
  const unsigned short* Ob = Opart + (size_t)(b * SPLIT_A) * CO * HW_;

  f32x4 acc[8];
#pragma unroll
  for (int mt = 0; mt < 8; ++mt)
    acc[mt] = *reinterpret_cast<const f32x4*>(&bo[fh * 128 + mt * 16 + quad * 4]);

#pragma unroll
  for (int ks = 0; ks < 2; ++ks) {
    short8 afh[8], afl[8];
#pragma unroll
    for (int mt = 0; mt < 8; ++mt) {
      int row = mt * 16 + lq;
      int addr = (row * 128 + ks * 64 + quad * 16) ^ ((row & 7) << 4);
      afh[mt] = *reinterpret_cast<const short8*>(whb + addr);
      afl[mt] = *reinterpret_cast<const short8*>(wlb + addr);
    }
#pragma unroll
    for (int s = 0; s < SPLIT_A; ++s) {
      short8 bf;
#pragma unroll
      for (int j = 0; j < 8; ++j)
        bf[j] = (short)Ob[(size_t)(s * CO + ks * 32 + quad * 8 + j) * HW_ + n];
#pragma unroll
      for (int mt = 0; mt < 8; ++mt) {
        acc[mt] = __builtin_amdgcn_mfma_f32_16x16x32_bf16(afh[mt], bf, acc[mt], 0, 0, 0);
        acc[mt] = __builtin_amdgcn_mfma_f32_16x16x32_bf16(afl[mt], bf, acc[mt], 0, 0, 0);
      }
    }
  }

#pragma unroll
  for (int mt = 0; mt < 8; ++mt) {
    int f = fh * 128 + mt * 16 + quad * 4;
#pragma unroll
    for (int r = 0; r < 4; ++r)
      out[((size_t)b * CIN + f + r) * HW_ + n] = acc[mt][r];
  }
}

extern "C" void kernel_launch(void* const* d_in, const int* in_sizes, int n_in,
                              void* d_out, int out_size, void* d_ws, size_t ws_size,
                              hipStream_t stream) {
  const float* x  = (const float*)d_in[0];
  const float* wq = (const float*)d_in[1];
  const float* bq = (const float*)d_in[2];
  const float* wk = (const float*)d_in[3];
  const float* bk = (const float*)d_in[4];
  const float* wv = (const float*)d_in[5];
  const float* bv = (const float*)d_in[6];
  const float* wo = (const float*)d_in[7];
  const float* bo = (const float*)d_in[8];
  float* out = (float*)d_out;

  char* ws = (char*)d_ws;
  unsigned short* qT    = (unsigned short*)(ws);               // 2 MB   [b][4096][64] bf16
  unsigned short* kT    = (unsigned short*)(ws + (2u << 20));  // 2 MB   [b][4096][64] bf16
  unsigned short* v     = (unsigned short*)(ws + (4u << 20));  // 2 MB   [b][64][4096] bf16
  unsigned short* Opart = (unsigned short*)(ws + (6u << 20));  // 16.8MB [b][8][64][4096] bf16
  float* ml             = (float*)(ws + (23u << 20));          // 64 KB  [b][4096] f32
  float2* parts         = (float2*)(ws + (24u << 20));         // 1 MB   [b][4096][8] float2

  qkv_kernel<<<dim3(64, 3, 4), 256, 0, stream>>>(x, wq, bq, wk, bk, wv, bv, qT, kT, v);
  stats_kernel<<<dim3(1024), 256, 0, stream>>>(qT, kT, parts);
  combine_kernel<<<dim3(BB * HW_ / 256), 256, 0, stream>>>(parts, ml);
  apply_kernel<<<dim3(1024), 256, 0, stream>>>(qT, kT, v, ml, Opart);
  outproj_kernel<<<dim3(64, 2, 4), 256, 0, stream>>>(Opart, wo, bo, out);
}

// Round 18
// 75.616 us; speedup vs baseline: 1.7175x; 1.0543x over previous
//
#include <hip/hip_runtime.h>
#include <hip/hip_bf16.h>

#define BB 4
#define CIN 256
#define CO 64
#define HW_ 4096
#define SPLIT_A 8
#define SPLIT_S 8
#define DCHUNK_A (HW_ / SPLIT_A)   // 512
#define ECHUNK_S (HW_ / SPLIT_S)   // 512

typedef __attribute__((ext_vector_type(8))) short short8;
typedef __attribute__((ext_vector_type(4))) float f32x4;
typedef __attribute__((ext_vector_type(16))) float f32x16;
typedef __attribute__((ext_vector_type(4))) unsigned uint4v;
typedef __attribute__((ext_vector_type(2))) unsigned uint2v;

__device__ inline unsigned short f2bf(float f) {
  union { float f; unsigned u; } x; x.f = f;
  unsigned r = x.u + 0x7fffu + ((x.u >> 16) & 1u);  // RNE
  return (unsigned short)(r >> 16);
}
__device__ inline float bf2f(unsigned short h) {
  union { unsigned u; float f; } x; x.u = ((unsigned)h) << 16;
  return x.f;
}
__device__ inline unsigned packbf2(float a, float b) {
  __hip_bfloat162 t = __float22bfloat162_rn(float2{a, b});
  union { __hip_bfloat162 h; unsigned u; } c; c.h = t; return c.u;
}
__device__ inline void gl_lds16(const void* g, void* l) {
  __builtin_amdgcn_global_load_lds(
      (const __attribute__((address_space(1))) unsigned int*)g,
      (__attribute__((address_space(3))) unsigned int*)l, 16, 0, 0);
}

// ---------------------------------------------------------------------------
// K1: QKV projection as MFMA GEMM (r14-verified, unchanged).
// ---------------------------------------------------------------------------
__global__ __launch_bounds__(256, 3) void qkv_kernel(
    const float* __restrict__ x,
    const float* __restrict__ wq, const float* __restrict__ bq,
    const float* __restrict__ wk, const float* __restrict__ bk,
    const float* __restrict__ wv, const float* __restrict__ bv,
    unsigned short* __restrict__ qT, unsigned short* __restrict__ kT,
    unsigned short* __restrict__ v)
{
  const int b = blockIdx.z;
  const int which = blockIdx.y;
  const int n0 = blockIdx.x * 64;
  const int tid = threadIdx.x;
  const int w = tid >> 6, lane = tid & 63;
  const int lq = lane & 15, quad = lane >> 4;

  const float* W  = (which == 0) ? wq : (which == 1) ? wk : wv;
  const float* Bb = (which == 0) ? bq : (which == 1) ? bk : bv;

  __shared__ unsigned short w_lds[64 * 256];
  unsigned char* wbytes = reinterpret_cast<unsigned char*>(w_lds);

#pragma unroll
  for (int i = 0; i < 16; ++i) {
    int L = i * 256 + tid;
    int row = L >> 6, col4 = L & 63;
    float4 w4 = *reinterpret_cast<const float4*>(&W[row * 256 + col4 * 4]);
    ushort4 p;
    p.x = f2bf(w4.x); p.y = f2bf(w4.y); p.z = f2bf(w4.z); p.w = f2bf(w4.w);
    int addr = (row * 512 + col4 * 8) ^ ((row & 7) << 4);
    *reinterpret_cast<ushort4*>(wbytes + addr) = p;
  }
  __syncthreads();

  const int n = n0 + w * 16 + lq;
  const float* xb = x + (size_t)b * CIN * HW_ + n;

  const f32x4 zero = {0.f, 0.f, 0.f, 0.f};
  f32x4 acc[4];
#pragma unroll
  for (int mt = 0; mt < 4; ++mt) acc[mt] = zero;

  for (int ks = 0; ks < 8; ++ks) {
    float xv[8];
#pragma unroll
    for (int j = 0; j < 8; ++j)
      xv[j] = xb[(size_t)(ks * 32 + quad * 8 + j) * HW_];
    short8 bhi, blo;
#pragma unroll
    for (int j = 0; j < 8; ++j) {
      unsigned short h = f2bf(xv[j]);
      bhi[j] = (short)h;
      blo[j] = (short)f2bf(xv[j] - bf2f(h));
    }
#pragma unroll
    for (int mt = 0; mt < 4; ++mt) {
      int addr = ((mt * 16 + lq) * 512 + ks * 64 + quad * 16) ^ ((lq & 7) << 4);
      short8 af = *reinterpret_cast<const short8*>(wbytes + addr);
      acc[mt] = __builtin_amdgcn_mfma_f32_16x16x32_bf16(af, bhi, acc[mt], 0, 0, 0);
      acc[mt] = __builtin_amdgcn_mfma_f32_16x16x32_bf16(af, blo, acc[mt], 0, 0, 0);
    }
  }

  float4 bias4[4];
#pragma unroll
  for (int mt = 0; mt < 4; ++mt)
    bias4[mt] = *reinterpret_cast<const float4*>(&Bb[mt * 16 + quad * 4]);

  if (which < 2) {
    unsigned short* outp = ((which == 0) ? qT : kT) + ((size_t)b * HW_ + n) * 64;
#pragma unroll
    for (int mt = 0; mt < 4; ++mt) {
      ushort4 p;
      p.x = f2bf(acc[mt][0] + bias4[mt].x);
      p.y = f2bf(acc[mt][1] + bias4[mt].y);
      p.z = f2bf(acc[mt][2] + bias4[mt].z);
      p.w = f2bf(acc[mt][3] + bias4[mt].w);
      *reinterpret_cast<ushort4*>(&outp[mt * 16 + quad * 4]) = p;
    }
  } else {
#pragma unroll
    for (int mt = 0; mt < 4; ++mt) {
      float bb[4] = {bias4[mt].x, bias4[mt].y, bias4[mt].z, bias4[mt].w};
#pragma unroll
      for (int r = 0; r < 4; ++r)
        v[((size_t)b * CO + mt * 16 + quad * 4 + r) * HW_ + n] = f2bf(acc[mt][r] + bb[r]);
    }
  }
}

// ---------------------------------------------------------------------------
// K2a: stats, 2-phase double-buffered (T3 minimum recipe). 64-e tiles,
// dbuf 16 KB; stage t+1 issued BEFORE compute t; one barrier per tile.
// Read swizzle identical to r14 (row stride 128 B).
// ---------------------------------------------------------------------------
__global__ __launch_bounds__(256, 3) void stats_kernel(
    const unsigned short* __restrict__ qT,
    const unsigned short* __restrict__ kT,
    float2* __restrict__ parts)
{
  const int id = blockIdx.x;
  const int sw = (id & 7) * 128 + (id >> 3);   // XCD swizzle (1024 blocks)
  const int dtile = sw & 31;
  const int esplit = (sw >> 5) & 7;
  const int b = sw >> 8;
  const int tid = threadIdx.x;
  const int w = tid >> 6, lane = tid & 63;
  const int lo = lane & 31, h = lane >> 5;

  __shared__ __align__(16) unsigned char k_lds[2][8192];  // [64 e][64 c] swz x2

  const size_t base = (size_t)b * HW_ * CO;
  const int d0 = dtile * 128 + w * 32;

  short8 qf[4];
#pragma unroll
  for (int ks = 0; ks < 4; ++ks)
    qf[ks] = *reinterpret_cast<const short8*>(&qT[base + (size_t)(d0 + lo) * 64 + ks * 16 + h * 8]);

  float m_run = -3.0e38f, l_run = 0.f;
  const char* kT_bytes = reinterpret_cast<const char*>(kT) + base * 2;
  const int e_beg = esplit * ECHUNK_S;
  const int NT = ECHUNK_S / 64;   // 8

  auto stage = [&](int t, int buf) {
    const int eb = e_beg + t * 64;
#pragma unroll
    for (int j = 0; j < 2; ++j) {
      int chunk = w * 2 + j;
      int row = chunk * 8 + (lane >> 3);
      int cp = (lane & 7) * 16;
      gl_lds16(kT_bytes + (size_t)(eb + row) * 128 + (cp ^ ((row & 7) << 4)),
               k_lds[buf] + chunk * 1024);
    }
  };

  stage(0, 0);
  __syncthreads();

  for (int t = 0; t < NT; ++t) {
    if (t + 1 < NT) stage(t + 1, (t + 1) & 1);
    const unsigned char* kb = k_lds[t & 1];
#pragma unroll
    for (int et = 0; et < 2; ++et) {
      const int er = et * 32 + lo;
      f32x16 T;
#pragma unroll
      for (int i = 0; i < 16; ++i) T[i] = 0.f;
#pragma unroll
      for (int ks = 0; ks < 4; ++ks) {
        const short8 kfr = *reinterpret_cast<const short8*>(
            kb + er * 128 + ((ks * 32 + h * 16) ^ ((er & 7) << 4)));
        T = __builtin_amdgcn_mfma_f32_32x32x16_bf16(kfr, qf[ks], T, 0, 0, 0);
      }
      float tmax = T[0];
#pragma unroll
      for (int r = 1; r < 16; ++r) tmax = fmaxf(tmax, T[r]);
      tmax = fmaxf(tmax, __shfl_xor(tmax, 32));
      float m_new = fmaxf(m_run, tmax);
      float lsum = 0.f;
#pragma unroll
      for (int r = 0; r < 16; ++r) lsum += __expf(T[r] - m_new);
      lsum += __shfl_xor(lsum, 32);
      l_run = l_run * __expf(m_run - m_new) + lsum;
      m_run = m_new;
    }
    __syncthreads();
  }
  if (h == 0)
    parts[((size_t)b * HW_ + d0 + lo) * SPLIT_S + esplit] = make_float2(m_run, l_run);
}

// ---------------------------------------------------------------------------
// K2b: merge per-split stats (exact).
// ---------------------------------------------------------------------------
__global__ __launch_bounds__(256) void combine_kernel(
    const float2* __restrict__ parts, float* __restrict__ ml)
{
  const int r = blockIdx.x * 256 + threadIdx.x;
  float2 p[SPLIT_S];
#pragma unroll
  for (int i = 0; i < SPLIT_S; ++i) p[i] = parts[(size_t)r * SPLIT_S + i];
  float M = p[0].x;
#pragma unroll
  for (int i = 1; i < SPLIT_S; ++i) M = fmaxf(M, p[i].x);
  float L = 0.f;
#pragma unroll
  for (int i = 0; i < SPLIT_S; ++i) L += p[i].y * __expf(p[i].x - M);
  ml[r] = M + __logf(L);
}

// ---------------------------------------------------------------------------
// K3: apply, 2-phase double-buffered (T3 minimum recipe). 64-d tiles,
// dbuf 2x(8+8)=32 KB; stage t+1 before compute t; one barrier per tile.
// Compute math identical to r14 (32x32 swapped-QK, in-register P).
// ---------------------------------------------------------------------------
__global__ __launch_bounds__(256, 3) void apply_kernel(
    const unsigned short* __restrict__ qT,
    const unsigned short* __restrict__ kT,
    const unsigned short* __restrict__ vv,
    const float* __restrict__ ml,
    unsigned short* __restrict__ Opart)
{
  const int id = blockIdx.x;
  const int sw = (id & 7) * 128 + (id >> 3);   // XCD swizzle (1024 blocks)
  const int et = sw & 31;
  const int split = (sw >> 5) & 7;
  const int b = sw >> 8;
  const int tid = threadIdx.x;
  const int w = tid >> 6, lane = tid & 63;
  const int lo = lane & 31, h = lane >> 5;

  __shared__ __align__(16) unsigned char lds_all[32768];
  // layout: q buf0 @0, q buf1 @8192, v buf0 @16384, v buf1 @24576
  // each q buf: [64 d][64 c] swz (8 KB); each v buf: [64 c][64 d] swz (8 KB)

  const size_t base = (size_t)b * HW_ * CO;
  const int e0 = et * 128;
  const int e = e0 + w * 32 + lo;

  short8 kf[4];
#pragma unroll
  for (int ks = 0; ks < 4; ++ks)
    kf[ks] = *reinterpret_cast<const short8*>(&kT[base + (size_t)e * 64 + ks * 16 + h * 8]);

  f32x16 Of0, Of1;
#pragma unroll
  for (int i = 0; i < 16; ++i) { Of0[i] = 0.f; Of1[i] = 0.f; }

  const char* qT_bytes = reinterpret_cast<const char*>(qT) + base * 2;
  const char* v_bytes = reinterpret_cast<const char*>(vv) + base * 2;
  const float* mlb = ml + (size_t)b * HW_;

  const int d_beg = split * DCHUNK_A;
  const int NT = DCHUNK_A / 64;   // 8

  auto stage = [&](int t, int buf) {
    const int dt = d_beg + t * 64;
#pragma unroll
    for (int j = 0; j < 2; ++j) {
      int chunk = w * 2 + j;
      int row = chunk * 8 + (lane >> 3);
      int cp = (lane & 7) * 16;
      gl_lds16(qT_bytes + (size_t)(dt + row) * 128 + (cp ^ ((row & 7) << 4)),
               lds_all + buf * 8192 + chunk * 1024);
      gl_lds16(v_bytes + (size_t)row * 8192 + dt * 2 + (cp ^ ((row & 7) << 4)),
               lds_all + 16384 + buf * 8192 + chunk * 1024);
    }
  };

  stage(0, 0);
  __syncthreads();

  for (int t = 0; t < NT; ++t) {
    if (t + 1 < NT) stage(t + 1, (t + 1) & 1);
    const int dt = d_beg + t * 64;
    const unsigned char* qb = lds_all + (t & 1) * 8192;
    const unsigned char* vb = lds_all + 16384 + (t & 1) * 8192;
#pragma unroll
    for (int nt = 0; nt < 2; ++nt) {
      const int db = dt + nt * 32;
      const int lrow = nt * 32 + lo;
      f32x16 T;
#pragma unroll
      for (int i = 0; i < 16; ++i) T[i] = 0.f;
#pragma unroll
      for (int ks = 0; ks < 4; ++ks) {
        const short8 qfr = *reinterpret_cast<const short8*>(
            qb + lrow * 128 + ((ks * 32 + h * 16) ^ ((lrow & 7) << 4)));
        T = __builtin_amdgcn_mfma_f32_32x32x16_bf16(qfr, kf[ks], T, 0, 0, 0);
      }
      float p[16];
#pragma unroll
      for (int q = 0; q < 4; ++q) {
        f32x4 m4 = *reinterpret_cast<const f32x4*>(&mlb[db + q * 8 + h * 4]);
#pragma unroll
        for (int r = 0; r < 4; ++r)
          p[q * 4 + r] = __expf(T[q * 4 + r] - m4[r]);
      }
      unsigned pk[8];
#pragma unroll
      for (int m = 0; m < 8; ++m) pk[m] = packbf2(p[2 * m], p[2 * m + 1]);
#pragma unroll
      for (int kk = 0; kk < 2; ++kk) {
        uint2v s0 = __builtin_amdgcn_permlane32_swap(pk[kk * 4 + 0], pk[kk * 4 + 2], false, false);
        uint2v s1 = __builtin_amdgcn_permlane32_swap(pk[kk * 4 + 1], pk[kk * 4 + 3], false, false);
        uint4v pw_;
        pw_[0] = s0[0]; pw_[1] = s1[0]; pw_[2] = s0[1]; pw_[3] = s1[1];
        const short8 pf = *reinterpret_cast<const short8*>(&pw_);
        const int dcol = (nt * 32 + kk * 16) * 2 + h * 16;   // < 128
        {
          const int row = lo;
          const short8 vf = *reinterpret_cast<const short8*>(
              vb + row * 128 + (dcol ^ ((row & 7) << 4)));
          Of0 = __builtin_amdgcn_mfma_f32_32x32x16_bf16(vf, pf, Of0, 0, 0, 0);
        }
        {
          const int row = 32 + lo;
          const short8 vf = *reinterpret_cast<const short8*>(
              vb + row * 128 + (dcol ^ ((row & 7) << 4)));
          Of1 = __builtin_amdgcn_mfma_f32_32x32x16_bf16(vf, pf, Of1, 0, 0, 0);
        }
      }
    }
    __syncthreads();
  }

  // epilogue: transpose via LDS (overlay first 16 KB), full-line NT stores
  unsigned short* o_lds = reinterpret_cast<unsigned short*>(lds_all);  // [64 c][128 e]
#pragma unroll
  for (int reg = 0; reg < 16; ++reg) {
    int rr = (reg & 3) + 8 * (reg >> 2) + 4 * h;
    o_lds[rr * 128 + w * 32 + lo] = f2bf(Of0[reg]);
    o_lds[(32 + rr) * 128 + w * 32 + lo] = f2bf(Of1[reg]);
  }
  __syncthreads();
  {
    const int c = tid >> 4;            // 0..15
    const int ee = (tid & 15) * 8;     // 16B/lane; 16 lanes = 256B contiguous
#pragma unroll
    for (int p = 0; p < 4; ++p) {
      int cc = p * 16 + c;
      f32x4 wv_ = *reinterpret_cast<const f32x4*>(&o_lds[cc * 128 + ee]);
      __builtin_nontemporal_store(wv_, reinterpret_cast<f32x4*>(
          &Opart[((size_t)(b * SPLIT_A + split) * CO + cc) * HW_ + e0 + ee]));
    }
  }
}

// ---------------------------------------------------------------------------
// K4: outproj as MFMA GEMM (r17-verified, unchanged).
// ---------------------------------------------------------------------------
__global__ __launch_bounds__(256) void outproj_kernel(
    const unsigned short* __restrict__ Opart, const float* __restrict__ wo,
    const float* __restrict__ bo, float* __restrict__ out)
{
  const int b = blockIdx.z;
  const int fh = blockIdx.y;
  const int n0 = blockIdx.x * 64;
  const int tid = threadIdx.x;
  const int w = tid >> 6, lane = tid & 63;
  const int lq = lane & 15, quad = lane >> 4;

  __shared__ __align__(16) unsigned short whi_lds[128 * 64];
  __shared__ __align__(16) unsigned short wlo_lds[128 * 64];
  unsigned char* whb = reinterpret_cast<unsigned char*>(whi_lds);
  unsigned char* wlb = reinterpret_cast<unsigned char*>(wlo_lds);

#pragma unroll
  for (int i = 0; i < 8; ++i) {
    int L = i * 256 + tid;
    int row = L >> 4, col4 = L & 15;
    float4 w4 = *reinterpret_cast<const float4*>(&wo[(size_t)(fh * 128 + row) * 64 + col4 * 4]);
    ushort4 hi, lo;
    hi.x = f2bf(w4.x); lo.x = f2bf(w4.x - bf2f(hi.x));
    hi.y = f2bf(w4.y); lo.y = f2bf(w4.y - bf2f(hi.y));
    hi.z = f2bf(w4.z); lo.z = f2bf(w4.z - bf2f(hi.z));
    hi.w = f2bf(w4.w); lo.w = f2bf(w4.w - bf2f(hi.w));
    int addr = (row * 128 + col4 * 8) ^ ((row & 7) << 4);
    *reinterpret_cast<ushort4*>(whb + addr) = hi;
    *reinterpret_cast<ushort4*>(wlb + addr) = lo;
  }
  __syncthreads();

  const int n = n0 + w * 16 + lq;
  const unsigned short* Ob = Opart + (size_t)(b * SPLIT_A) * CO * HW_;

  f32x4 acc[8];
#pragma unroll
  for (int mt = 0; mt < 8; ++mt)
    acc[mt] = *reinterpret_cast<const f32x4*>(&bo[fh * 128 + mt * 16 + quad * 4]);

#pragma unroll
  for (int ks = 0; ks < 2; ++ks) {
    short8 afh[8], afl[8];
#pragma unroll
    for (int mt = 0; mt < 8; ++mt) {
      int row = mt * 16 + lq;
      int addr = (row * 128 + ks * 64 + quad * 16) ^ ((row & 7) << 4);
      afh[mt] = *reinterpret_cast<const short8*>(whb + addr);
      afl[mt] = *reinterpret_cast<const short8*>(wlb + addr);
    }
#pragma unroll
    for (int s = 0; s < SPLIT_A; ++s) {
      short8 bf;
#pragma unroll
      for (int j = 0; j < 8; ++j)
        bf[j] = (short)Ob[(size_t)(s * CO + ks * 32 + quad * 8 + j) * HW_ + n];
#pragma unroll
      for (int mt = 0; mt < 8; ++mt) {
        acc[mt] = __builtin_amdgcn_mfma_f32_16x16x32_bf16(afh[mt], bf, acc[mt], 0, 0, 0);
        acc[mt] = __builtin_amdgcn_mfma_f32_16x16x32_bf16(afl[mt], bf, acc[mt], 0, 0, 0);
      }
    }
  }

#pragma unroll
  for (int mt = 0; mt < 8; ++mt) {
    int f = fh * 128 + mt * 16 + quad * 4;
#pragma unroll
    for (int r = 0; r < 4; ++r)
      out[((size_t)b * CIN + f + r) * HW_ + n] = acc[mt][r];
  }
}

extern "C" void kernel_launch(void* const* d_in, const int* in_sizes, int n_in,
                              void* d_out, int out_size, void* d_ws, size_t ws_size,
                              hipStream_t stream) {
  const float* x  = (const float*)d_in[0];
  const float* wq = (const float*)d_in[1];
  const float* bq = (const float*)d_in[2];
  const float* wk = (const float*)d_in[3];
  const float* bk = (const float*)d_in[4];
  const float* wv = (const float*)d_in[5];
  const float* bv = (const float*)d_in[6];
  const float* wo = (const float*)d_in[7];
  const float* bo = (const float*)d_in[8];
  float* out = (float*)d_out;

  char* ws = (char*)d_ws;
  unsigned short* qT    = (unsigned short*)(ws);               // 2 MB   [b][4096][64] bf16
  unsigned short* kT    = (unsigned short*)(ws + (2u << 20));  // 2 MB   [b][4096][64] bf16
  unsigned short* v     = (unsigned short*)(ws + (4u << 20));  // 2 MB   [b][64][4096] bf16
  unsigned short* Opart = (unsigned short*)(ws + (6u << 20));  // 16.8MB [b][8][64][4096] bf16
  float* ml             = (float*)(ws + (23u << 20));          // 64 KB  [b][4096] f32
  float2* parts         = (float2*)(ws + (24u << 20));         // 1 MB   [b][4096][8] float2

  qkv_kernel<<<dim3(64, 3, 4), 256, 0, stream>>>(x, wq, bq, wk, bk, wv, bv, qT, kT, v);
  stats_kernel<<<dim3(1024), 256, 0, stream>>>(qT, kT, parts);
  combine_kernel<<<dim3(BB * HW_ / 256), 256, 0, stream>>>(parts, ml);
  apply_kernel<<<dim3(1024), 256, 0, stream>>>(qT, kT, v, ml, Opart);
  outproj_kernel<<<dim3(64, 2, 4), 256, 0, stream>>>(Opart, wo, bo, out);
}

// Round 19
// 74.874 us; speedup vs baseline: 1.7345x; 1.0099x over previous
//
#include <hip/hip_runtime.h>
#include <hip/hip_bf16.h>

#define BB 4
#define CIN 256
#define CO 64
#define HW_ 4096
#define SPLIT_A 8
#define SPLIT_S 8
#define DCHUNK_A (HW_ / SPLIT_A)   // 512
#define ECHUNK_S (HW_ / SPLIT_S)   // 512

typedef __attribute__((ext_vector_type(8))) short short8;
typedef __attribute__((ext_vector_type(4))) float f32x4;
typedef __attribute__((ext_vector_type(16))) float f32x16;
typedef __attribute__((ext_vector_type(4))) unsigned uint4v;
typedef __attribute__((ext_vector_type(2))) unsigned uint2v;

__device__ inline unsigned short f2bf(float f) {
  union { float f; unsigned u; } x; x.f = f;
  unsigned r = x.u + 0x7fffu + ((x.u >> 16) & 1u);  // RNE
  return (unsigned short)(r >> 16);
}
__device__ inline float bf2f(unsigned short h) {
  union { unsigned u; float f; } x; x.u = ((unsigned)h) << 16;
  return x.f;
}
__device__ inline unsigned packbf2(float a, float b) {
  __hip_bfloat162 t = __float22bfloat162_rn(float2{a, b});
  union { __hip_bfloat162 h; unsigned u; } c; c.h = t; return c.u;
}
__device__ inline void gl_lds16(const void* g, void* l) {
  __builtin_amdgcn_global_load_lds(
      (const __attribute__((address_space(1))) unsigned int*)g,
      (__attribute__((address_space(3))) unsigned int*)l, 16, 0, 0);
}

// ---------------------------------------------------------------------------
// K1: QKV projection as MFMA GEMM (r14-verified, unchanged).
// ---------------------------------------------------------------------------
__global__ __launch_bounds__(256, 3) void qkv_kernel(
    const float* __restrict__ x,
    const float* __restrict__ wq, const float* __restrict__ bq,
    const float* __restrict__ wk, const float* __restrict__ bk,
    const float* __restrict__ wv, const float* __restrict__ bv,
    unsigned short* __restrict__ qT, unsigned short* __restrict__ kT,
    unsigned short* __restrict__ v)
{
  const int b = blockIdx.z;
  const int which = blockIdx.y;
  const int n0 = blockIdx.x * 64;
  const int tid = threadIdx.x;
  const int w = tid >> 6, lane = tid & 63;
  const int lq = lane & 15, quad = lane >> 4;

  const float* W  = (which == 0) ? wq : (which == 1) ? wk : wv;
  const float* Bb = (which == 0) ? bq : (which == 1) ? bk : bv;

  __shared__ unsigned short w_lds[64 * 256];
  unsigned char* wbytes = reinterpret_cast<unsigned char*>(w_lds);

#pragma unroll
  for (int i = 0; i < 16; ++i) {
    int L = i * 256 + tid;
    int row = L >> 6, col4 = L & 63;
    float4 w4 = *reinterpret_cast<const float4*>(&W[row * 256 + col4 * 4]);
    ushort4 p;
    p.x = f2bf(w4.x); p.y = f2bf(w4.y); p.z = f2bf(w4.z); p.w = f2bf(w4.w);
    int addr = (row * 512 + col4 * 8) ^ ((row & 7) << 4);
    *reinterpret_cast<ushort4*>(wbytes + addr) = p;
  }
  __syncthreads();

  const int n = n0 + w * 16 + lq;
  const float* xb = x + (size_t)b * CIN * HW_ + n;

  const f32x4 zero = {0.f, 0.f, 0.f, 0.f};
  f32x4 acc[4];
#pragma unroll
  for (int mt = 0; mt < 4; ++mt) acc[mt] = zero;

  for (int ks = 0; ks < 8; ++ks) {
    float xv[8];
#pragma unroll
    for (int j = 0; j < 8; ++j)
      xv[j] = xb[(size_t)(ks * 32 + quad * 8 + j) * HW_];
    short8 bhi, blo;
#pragma unroll
    for (int j = 0; j < 8; ++j) {
      unsigned short h = f2bf(xv[j]);
      bhi[j] = (short)h;
      blo[j] = (short)f2bf(xv[j] - bf2f(h));
    }
#pragma unroll
    for (int mt = 0; mt < 4; ++mt) {
      int addr = ((mt * 16 + lq) * 512 + ks * 64 + quad * 16) ^ ((lq & 7) << 4);
      short8 af = *reinterpret_cast<const short8*>(wbytes + addr);
      acc[mt] = __builtin_amdgcn_mfma_f32_16x16x32_bf16(af, bhi, acc[mt], 0, 0, 0);
      acc[mt] = __builtin_amdgcn_mfma_f32_16x16x32_bf16(af, blo, acc[mt], 0, 0, 0);
    }
  }

  float4 bias4[4];
#pragma unroll
  for (int mt = 0; mt < 4; ++mt)
    bias4[mt] = *reinterpret_cast<const float4*>(&Bb[mt * 16 + quad * 4]);

  if (which < 2) {
    unsigned short* outp = ((which == 0) ? qT : kT) + ((size_t)b * HW_ + n) * 64;
#pragma unroll
    for (int mt = 0; mt < 4; ++mt) {
      ushort4 p;
      p.x = f2bf(acc[mt][0] + bias4[mt].x);
      p.y = f2bf(acc[mt][1] + bias4[mt].y);
      p.z = f2bf(acc[mt][2] + bias4[mt].z);
      p.w = f2bf(acc[mt][3] + bias4[mt].w);
      *reinterpret_cast<ushort4*>(&outp[mt * 16 + quad * 4]) = p;
    }
  } else {
#pragma unroll
    for (int mt = 0; mt < 4; ++mt) {
      float bb[4] = {bias4[mt].x, bias4[mt].y, bias4[mt].z, bias4[mt].w};
#pragma unroll
      for (int r = 0; r < 4; ++r)
        v[((size_t)b * CO + mt * 16 + quad * 4 + r) * HW_ + n] = f2bf(acc[mt][r] + bb[r]);
    }
  }
}

// ---------------------------------------------------------------------------
// K2: stats, 2-phase double-buffered (r18-verified, unchanged).
// ---------------------------------------------------------------------------
__global__ __launch_bounds__(256, 3) void stats_kernel(
    const unsigned short* __restrict__ qT,
    const unsigned short* __restrict__ kT,
    float2* __restrict__ parts)
{
  const int id = blockIdx.x;
  const int sw = (id & 7) * 128 + (id >> 3);   // XCD swizzle (1024 blocks)
  const int dtile = sw & 31;
  const int esplit = (sw >> 5) & 7;
  const int b = sw >> 8;
  const int tid = threadIdx.x;
  const int w = tid >> 6, lane = tid & 63;
  const int lo = lane & 31, h = lane >> 5;

  __shared__ __align__(16) unsigned char k_lds[2][8192];  // [64 e][64 c] swz x2

  const size_t base = (size_t)b * HW_ * CO;
  const int d0 = dtile * 128 + w * 32;

  short8 qf[4];
#pragma unroll
  for (int ks = 0; ks < 4; ++ks)
    qf[ks] = *reinterpret_cast<const short8*>(&qT[base + (size_t)(d0 + lo) * 64 + ks * 16 + h * 8]);

  float m_run = -3.0e38f, l_run = 0.f;
  const char* kT_bytes = reinterpret_cast<const char*>(kT) + base * 2;
  const int e_beg = esplit * ECHUNK_S;
  const int NT = ECHUNK_S / 64;   // 8

  auto stage = [&](int t, int buf) {
    const int eb = e_beg + t * 64;
#pragma unroll
    for (int j = 0; j < 2; ++j) {
      int chunk = w * 2 + j;
      int row = chunk * 8 + (lane >> 3);
      int cp = (lane & 7) * 16;
      gl_lds16(kT_bytes + (size_t)(eb + row) * 128 + (cp ^ ((row & 7) << 4)),
               k_lds[buf] + chunk * 1024);
    }
  };

  stage(0, 0);
  __syncthreads();

  for (int t = 0; t < NT; ++t) {
    if (t + 1 < NT) stage(t + 1, (t + 1) & 1);
    const unsigned char* kb = k_lds[t & 1];
#pragma unroll
    for (int et = 0; et < 2; ++et) {
      const int er = et * 32 + lo;
      f32x16 T;
#pragma unroll
      for (int i = 0; i < 16; ++i) T[i] = 0.f;
#pragma unroll
      for (int ks = 0; ks < 4; ++ks) {
        const short8 kfr = *reinterpret_cast<const short8*>(
            kb + er * 128 + ((ks * 32 + h * 16) ^ ((er & 7) << 4)));
        T = __builtin_amdgcn_mfma_f32_32x32x16_bf16(kfr, qf[ks], T, 0, 0, 0);
      }
      float tmax = T[0];
#pragma unroll
      for (int r = 1; r < 16; ++r) tmax = fmaxf(tmax, T[r]);
      tmax = fmaxf(tmax, __shfl_xor(tmax, 32));
      float m_new = fmaxf(m_run, tmax);
      float lsum = 0.f;
#pragma unroll
      for (int r = 0; r < 16; ++r) lsum += __expf(T[r] - m_new);
      lsum += __shfl_xor(lsum, 32);
      l_run = l_run * __expf(m_run - m_new) + lsum;
      m_run = m_new;
    }
    __syncthreads();
  }
  if (h == 0)
    parts[((size_t)b * HW_ + d0 + lo) * SPLIT_S + esplit] = make_float2(m_run, l_run);
}

// ---------------------------------------------------------------------------
// K3: apply, 2-phase dbuf (r18-verified) + FUSED ml merge: each block
// computes exact logsumexp over the 8 splits for its own 512-d chunk at
// start (overlapped with first stage), parks it in 2 KB LDS.
// ---------------------------------------------------------------------------
__global__ __launch_bounds__(256, 3) void apply_kernel(
    const unsigned short* __restrict__ qT,
    const unsigned short* __restrict__ kT,
    const unsigned short* __restrict__ vv,
    const float2* __restrict__ parts,
    unsigned short* __restrict__ Opart)
{
  const int id = blockIdx.x;
  const int sw = (id & 7) * 128 + (id >> 3);   // XCD swizzle (1024 blocks)
  const int et = sw & 31;
  const int split = (sw >> 5) & 7;
  const int b = sw >> 8;
  const int tid = threadIdx.x;
  const int w = tid >> 6, lane = tid & 63;
  const int lo = lane & 31, h = lane >> 5;

  __shared__ __align__(16) unsigned char lds_all[32768];
  __shared__ __align__(16) float ml_lds[DCHUNK_A];   // 2 KB
  // lds_all: q buf0 @0, q buf1 @8192, v buf0 @16384, v buf1 @24576

  const size_t base = (size_t)b * HW_ * CO;
  const int e0 = et * 128;
  const int e = e0 + w * 32 + lo;
  const int d_beg = split * DCHUNK_A;

  const char* qT_bytes = reinterpret_cast<const char*>(qT) + base * 2;
  const char* v_bytes = reinterpret_cast<const char*>(vv) + base * 2;

  auto stage = [&](int t, int buf) {
    const int dt = d_beg + t * 64;
#pragma unroll
    for (int j = 0; j < 2; ++j) {
      int chunk = w * 2 + j;
      int row = chunk * 8 + (lane >> 3);
      int cp = (lane & 7) * 16;
      gl_lds16(qT_bytes + (size_t)(dt + row) * 128 + (cp ^ ((row & 7) << 4)),
               lds_all + buf * 8192 + chunk * 1024);
      gl_lds16(v_bytes + (size_t)row * 8192 + dt * 2 + (cp ^ ((row & 7) << 4)),
               lds_all + 16384 + buf * 8192 + chunk * 1024);
    }
  };

  stage(0, 0);   // async loads in flight while we merge ml below

  // fused combine: ml[d] = M + log sum_s l_s exp(m_s - M), exact
#pragma unroll
  for (int i = 0; i < DCHUNK_A / 256; ++i) {
    const int dl = i * 256 + tid;
    const float2* pp = &parts[((size_t)b * HW_ + d_beg + dl) * SPLIT_S];
    float2 p[SPLIT_S];
#pragma unroll
    for (int s = 0; s < SPLIT_S; ++s) p[s] = pp[s];
    float M = p[0].x;
#pragma unroll
    for (int s = 1; s < SPLIT_S; ++s) M = fmaxf(M, p[s].x);
    float L = 0.f;
#pragma unroll
    for (int s = 0; s < SPLIT_S; ++s) L += p[s].y * __expf(p[s].x - M);
    ml_lds[dl] = M + __logf(L);
  }

  short8 kf[4];
#pragma unroll
  for (int ks = 0; ks < 4; ++ks)
    kf[ks] = *reinterpret_cast<const short8*>(&kT[base + (size_t)e * 64 + ks * 16 + h * 8]);

  f32x16 Of0, Of1;
#pragma unroll
  for (int i = 0; i < 16; ++i) { Of0[i] = 0.f; Of1[i] = 0.f; }

  __syncthreads();   // drains stage(0) vmcnt AND publishes ml_lds

  const int NT = DCHUNK_A / 64;   // 8
  for (int t = 0; t < NT; ++t) {
    if (t + 1 < NT) stage(t + 1, (t + 1) & 1);
    const int dt = d_beg + t * 64;
    const unsigned char* qb = lds_all + (t & 1) * 8192;
    const unsigned char* vb = lds_all + 16384 + (t & 1) * 8192;
#pragma unroll
    for (int nt = 0; nt < 2; ++nt) {
      const int dbl = (dt - d_beg) + nt * 32;     // local d base
      const int lrow = nt * 32 + lo;
      f32x16 T;
#pragma unroll
      for (int i = 0; i < 16; ++i) T[i] = 0.f;
#pragma unroll
      for (int ks = 0; ks < 4; ++ks) {
        const short8 qfr = *reinterpret_cast<const short8*>(
            qb + lrow * 128 + ((ks * 32 + h * 16) ^ ((lrow & 7) << 4)));
        T = __builtin_amdgcn_mfma_f32_32x32x16_bf16(qfr, kf[ks], T, 0, 0, 0);
      }
      float p[16];
#pragma unroll
      for (int q = 0; q < 4; ++q) {
        f32x4 m4 = *reinterpret_cast<const f32x4*>(&ml_lds[dbl + q * 8 + h * 4]);
#pragma unroll
        for (int r = 0; r < 4; ++r)
          p[q * 4 + r] = __expf(T[q * 4 + r] - m4[r]);
      }
      unsigned pk[8];
#pragma unroll
      for (int m = 0; m < 8; ++m) pk[m] = packbf2(p[2 * m], p[2 * m + 1]);
#pragma unroll
      for (int kk = 0; kk < 2; ++kk) {
        uint2v s0 = __builtin_amdgcn_permlane32_swap(pk[kk * 4 + 0], pk[kk * 4 + 2], false, false);
        uint2v s1 = __builtin_amdgcn_permlane32_swap(pk[kk * 4 + 1], pk[kk * 4 + 3], false, false);
        uint4v pw_;
        pw_[0] = s0[0]; pw_[1] = s1[0]; pw_[2] = s0[1]; pw_[3] = s1[1];
        const short8 pf = *reinterpret_cast<const short8*>(&pw_);
        const int dcol = (nt * 32 + kk * 16) * 2 + h * 16;   // < 128
        {
          const int row = lo;
          const short8 vf = *reinterpret_cast<const short8*>(
              vb + row * 128 + (dcol ^ ((row & 7) << 4)));
          Of0 = __builtin_amdgcn_mfma_f32_32x32x16_bf16(vf, pf, Of0, 0, 0, 0);
        }
        {
          const int row = 32 + lo;
          const short8 vf = *reinterpret_cast<const short8*>(
              vb + row * 128 + (dcol ^ ((row & 7) << 4)));
          Of1 = __builtin_amdgcn_mfma_f32_32x32x16_bf16(vf, pf, Of1, 0, 0, 0);
        }
      }
    }
    __syncthreads();
  }

  // epilogue: transpose via LDS (overlay first 16 KB), full-line NT stores
  unsigned short* o_lds = reinterpret_cast<unsigned short*>(lds_all);  // [64 c][128 e]
#pragma unroll
  for (int reg = 0; reg < 16; ++reg) {
    int rr = (reg & 3) + 8 * (reg >> 2) + 4 * h;
    o_lds[rr * 128 + w * 32 + lo] = f2bf(Of0[reg]);
    o_lds[(32 + rr) * 128 + w * 32 + lo] = f2bf(Of1[reg]);
  }
  __syncthreads();
  {
    const int c = tid >> 4;            // 0..15
    const int ee = (tid & 15) * 8;     // 16B/lane; 16 lanes = 256B contiguous
#pragma unroll
    for (int p = 0; p < 4; ++p) {
      int cc = p * 16 + c;
      f32x4 wv_ = *reinterpret_cast<const f32x4*>(&o_lds[cc * 128 + ee]);
      __builtin_nontemporal_store(wv_, reinterpret_cast<f32x4*>(
          &Opart[((size_t)(b * SPLIT_A + split) * CO + cc) * HW_ + e0 + ee]));
    }
  }
}

// ---------------------------------------------------------------------------
// K4: outproj as MFMA GEMM (r17-verified, unchanged).
// ---------------------------------------------------------------------------
__global__ __launch_bounds__(256) void outproj_kernel(
    const unsigned short* __restrict__ Opart, const float* __restrict__ wo,
    const float* __restrict__ bo, float* __restrict__ out)
{
  const int b = blockIdx.z;
  const int fh = blockIdx.y;
  const int n0 = blockIdx.x * 64;
  const int tid = threadIdx.x;
  const int w = tid >> 6, lane = tid & 63;
  const int lq = lane & 15, quad = lane >> 4;

  __shared__ __align__(16) unsigned short whi_lds[128 * 64];
  __shared__ __align__(16) unsigned short wlo_lds[128 * 64];
  unsigned char* whb = reinterpret_cast<unsigned char*>(whi_lds);
  unsigned char* wlb = reinterpret_cast<unsigned char*>(wlo_lds);

#pragma unroll
  for (int i = 0; i < 8; ++i) {
    int L = i * 256 + tid;
    int row = L >> 4, col4 = L & 15;
    float4 w4 = *reinterpret_cast<const float4*>(&wo[(size_t)(fh * 128 + row) * 64 + col4 * 4]);
    ushort4 hi, lo;
    hi.x = f2bf(w4.x); lo.x = f2bf(w4.x - bf2f(hi.x));
    hi.y = f2bf(w4.y); lo.y = f2bf(w4.y - bf2f(hi.y));
    hi.z = f2bf(w4.z); lo.z = f2bf(w4.z - bf2f(hi.z));
    hi.w = f2bf(w4.w); lo.w = f2bf(w4.w - bf2f(hi.w));
    int addr = (row * 128 + col4 * 8) ^ ((row & 7) << 4);
    *reinterpret_cast<ushort4*>(whb + addr) = hi;
    *reinterpret_cast<ushort4*>(wlb + addr) = lo;
  }
  __syncthreads();

  const int n = n0 + w * 16 + lq;
  const unsigned short* Ob = Opart + (size_t)(b * SPLIT_A) * CO * HW_;

  f32x4 acc[8];
#pragma unroll
  for (int mt = 0; mt < 8; ++mt)
    acc[mt] = *reinterpret_cast<const f32x4*>(&bo[fh * 128 + mt * 16 + quad * 4]);

#pragma unroll
  for (int ks = 0; ks < 2; ++ks) {
    short8 afh[8], afl[8];
#pragma unroll
    for (int mt = 0; mt < 8; ++mt) {
      int row = mt * 16 + lq;
      int addr = (row * 128 + ks * 64 + quad * 16) ^ ((row & 7) << 4);
      afh[mt] = *reinterpret_cast<const short8*>(whb + addr);
      afl[mt] = *reinterpret_cast<const short8*>(wlb + addr);
    }
#pragma unroll
    for (int s = 0; s < SPLIT_A; ++s) {
      short8 bf;
#pragma unroll
      for (int j = 0; j < 8; ++j)
        bf[j] = (short)Ob[(size_t)(s * CO + ks * 32 + quad * 8 + j) * HW_ + n];
#pragma unroll
      for (int mt = 0; mt < 8; ++mt) {
        acc[mt] = __builtin_amdgcn_mfma_f32_16x16x32_bf16(afh[mt], bf, acc[mt], 0, 0, 0);
        acc[mt] = __builtin_amdgcn_mfma_f32_16x16x32_bf16(afl[mt], bf, acc[mt], 0, 0, 0);
      }
    }
  }

#pragma unroll
  for (int mt = 0; mt < 8; ++mt) {
    int f = fh * 128 + mt * 16 + quad * 4;
#pragma unroll
    for (int r = 0; r < 4; ++r)
      out[((size_t)b * CIN + f + r) * HW_ + n] = acc[mt][r];
  }
}

extern "C" void kernel_launch(void* const* d_in, const int* in_sizes, int n_in,
                              void* d_out, int out_size, void* d_ws, size_t ws_size,
                              hipStream_t stream) {
  const float* x  = (const float*)d_in[0];
  const float* wq = (const float*)d_in[1];
  const float* bq = (const float*)d_in[2];
  const float* wk = (const float*)d_in[3];
  const float* bk = (const float*)d_in[4];
  const float* wv = (const float*)d_in[5];
  const float* bv = (const float*)d_in[6];
  const float* wo = (const float*)d_in[7];
  const float* bo = (const float*)d_in[8];
  float* out = (float*)d_out;

  char* ws = (char*)d_ws;
  unsigned short* qT    = (unsigned short*)(ws);               // 2 MB   [b][4096][64] bf16
  unsigned short* kT    = (unsigned short*)(ws + (2u << 20));  // 2 MB   [b][4096][64] bf16
  unsigned short* v     = (unsigned short*)(ws + (4u << 20));  // 2 MB   [b][64][4096] bf16
  unsigned short* Opart = (unsigned short*)(ws + (6u << 20));  // 16.8MB [b][8][64][4096] bf16
  float2* parts         = (float2*)(ws + (24u << 20));         // 1 MB   [b][4096][8] float2

  qkv_kernel<<<dim3(64, 3, 4), 256, 0, stream>>>(x, wq, bq, wk, bk, wv, bv, qT, kT, v);
  stats_kernel<<<dim3(1024), 256, 0, stream>>>(qT, kT, parts);
  apply_kernel<<<dim3(1024), 256, 0, stream>>>(qT, kT, v, parts, Opart);
  outproj_kernel<<<dim3(64, 2, 4), 256, 0, stream>>>(Opart, wo, bo, out);
}